// Round 6
// baseline (145.333 us; speedup 1.0000x reference)
//
#include <hip/hip_runtime.h>

// Problem constants (from reference): B=4, N=2048, IN_F=512, HEADS=8, D=64
#define BB   4
#define NN   2048
#define INF  512
#define HH   8
#define DD   64
#define BH   (BB*HH)   // 32
#define NCK  16        // 128-row chunks per (b,h)
#define CKS  128       // chunk size

// ============================================================================
// A[b,h,i,j] = softmax_j( leaky_relu(q_j + k_i) ), H = A @ V.
// exp(leaky(x)) is piecewise multiplicative; sort j by q_j and the softmax
// collapses to prefix sums + position search. O(N·D).
// Harness 0xAA ws-poison (~88us, 2 fills/iter) is inside dur_us, untouchable.
// R14 FAILED: cooperative grid-sync = ~70us on 8 XCDs (cross-XCD atomics +
// L2 wb/inv + s_sleep spins). Kernel boundary IS the cheapest grid sync.
// R15 accounting: non-fill ~45.5us; kernel work models ~20us -> dispatch
// gaps ~3.5us each dominate. R16: 4 kernels -> 3. k_rank (slab j's are
// contiguous!) builds per-chunk member lists after ranking and register-
// accumulates per-(slab,chunk) partial sums -> global; k_out2 reduces the 8
// slab partials in its preamble. k_csum eliminated. Serve-loop sqc hoisted.
// ============================================================================

// ---- Kernel 1: fused V GEMM + q,k scores + sort keys -----------------------
// grid 256 x 256 thr. Block = 32 rows x 64 cols x full 512 k.
__global__ __launch_bounds__(256) void k_vq(
    const float* __restrict__ X, const float* __restrict__ Wv,
    const float* __restrict__ bv,
    const float* __restrict__ Wq, const float* __restrict__ bq,
    const float* __restrict__ Wk, const float* __restrict__ bk,
    float* __restrict__ V, float* __restrict__ ksg,
    unsigned long long* __restrict__ qk64)
{
  __shared__ float Ws[2][64][68];   // per-half W chunk [k][n], padded — 34.8KB
  __shared__ float red[128][16];    // kh=1 partial accs — 8KB
  __shared__ float Vs[32][65];      // reduced V rows for scores — 8.3KB
  const int t  = threadIdx.x;
  const int kh = t >> 7;            // k half: waves 0-1 -> 0, waves 2-3 -> 1
  const int u  = t & 127;
  const int tc = u & 15;            // col quad -> cols 4tc..4tc+3
  const int rg = u >> 4;            // row group -> rows 4rg..4rg+3
  const int r0 = blockIdx.x * 32;
  const int k0 = kh * 256;
  float acc[4][4];
  #pragma unroll
  for (int r = 0; r < 4; r++)
    #pragma unroll
    for (int c = 0; c < 4; c++) acc[r][c] = 0.f;

  for (int kc = 0; kc < 256; kc += 64) {
    __syncthreads();
    #pragma unroll
    for (int i = 0; i < 8; i++) {    // stage this half's 64k x 64n W chunk
      const int e4 = u + i * 128;    // 0..1023 float4 slots
      const int k  = e4 >> 4;
      const int n4 = (e4 & 15) * 4;
      *(float4*)(&Ws[kh][k][n4]) =
          *(const float4*)(Wv + (size_t)(k0 + kc + k) * DD + n4);
    }
    __syncthreads();
    const float* xp = X + (size_t)(r0 + rg * 4) * INF + k0 + kc;
    #pragma unroll 4
    for (int kk = 0; kk < 64; kk += 4) {
      float4 xr[4];
      #pragma unroll
      for (int r = 0; r < 4; r++)
        xr[r] = *(const float4*)(xp + (size_t)r * INF + kk);  // 16-lane bcast
      #pragma unroll
      for (int j = 0; j < 4; j++) {
        const float4 w4 = *(const float4*)(&Ws[kh][kk + j][tc * 4]);
        #pragma unroll
        for (int r = 0; r < 4; r++) {
          const float x = (j == 0) ? xr[r].x : (j == 1) ? xr[r].y
                        : (j == 2) ? xr[r].z : xr[r].w;
          acc[r][0] += x * w4.x;  acc[r][1] += x * w4.y;
          acc[r][2] += x * w4.z;  acc[r][3] += x * w4.w;
        }
      }
    }
  }

  // ---- reduce the two k-halves, add bias, publish V (global + LDS) ----
  __syncthreads();
  if (kh == 1) {
    #pragma unroll
    for (int r = 0; r < 4; r++)
      *(float4*)(&red[u][r * 4]) = *(const float4*)(&acc[r][0]);
  }
  __syncthreads();
  if (kh == 0) {
    const float4 bb = *(const float4*)(bv + tc * 4);
    #pragma unroll
    for (int r = 0; r < 4; r++) {
      const float4 p = *(const float4*)(&red[u][r * 4]);
      float4 o;
      o.x = acc[r][0] + p.x + bb.x;  o.y = acc[r][1] + p.y + bb.y;
      o.z = acc[r][2] + p.z + bb.z;  o.w = acc[r][3] + p.w + bb.w;
      *(float4*)(V + (size_t)(r0 + rg * 4 + r) * DD + tc * 4) = o;
      Vs[rg * 4 + r][tc * 4]     = o.x;  Vs[rg * 4 + r][tc * 4 + 1] = o.y;
      Vs[rg * 4 + r][tc * 4 + 2] = o.z;  Vs[rg * 4 + r][tc * 4 + 3] = o.w;
    }
  }
  __syncthreads();

  // ---- scores: thread = (row, h), does both q and k dot-64 ----
  const int row = t >> 3;
  const int h   = t & 7;
  float sq = bq[h], sk = bk[h];
  #pragma unroll 8
  for (int dd = 0; dd < DD; dd++) {
    const float v = Vs[row][dd];
    sq += v * Wq[dd * HH + h];
    sk += v * Wk[dd * HH + h];
  }
  const int grow = r0 + row;
  const int b = grow >> 11, n = grow & (NN - 1);
  const int bh = b * HH + h;
  ksg[bh * NN + n] = sk;
  // tie-proof orderable key: ascending u64 order == ascending (float, idx)
  unsigned uo = __float_as_uint(sq);
  uo = (uo & 0x80000000u) ? ~uo : (uo | 0x80000000u);
  qk64[(size_t)bh * NN + n] = ((unsigned long long)uo << 32) | (unsigned)n;
}

// -------- Kernel 2: LDS-fed O(N^2) rank + scatter + chunk partial sums ------
// 256 blocks x 256 thr. Block = (bh, 256-j slab). Stage all 2048 keys (16KB);
// rank via LDS-broadcast b128 compares (R12). NEW (R16): the slab's j's are
// contiguous, so after ranking we bucket them by dest chunk (LDS lists) and
// each wave register-accumulates 4 chunks' e1·V / e2·V sums (coalesced V row
// reads, no LDS rmw chains), writing per-(slab,chunk) partials to global.
// This absorbs k_csum: one fewer dispatch + gap.
__global__ __launch_bounds__(256) void k_rank(
    const unsigned long long* __restrict__ qk64,
    const float* __restrict__ V,
    float* __restrict__ sqs, unsigned short* __restrict__ idxg,
    float* __restrict__ PS1, float* __restrict__ PS2,
    float* __restrict__ PL1, float* __restrict__ PL2)
{
  __shared__ __align__(16) unsigned long long keys[NN];  // 16 KB
  __shared__ int cnt[4][256];                            // 4 KB
  __shared__ unsigned short mlist[NCK][CKS];             // 4 KB member lists
  __shared__ int mcnt[NCK];
  const int t    = threadIdx.x;
  const int bh   = blockIdx.x >> 3;
  const int slab = blockIdx.x & 7;
  const int jq   = t & 63;
  const int kq   = t >> 6;
  const unsigned long long* __restrict__ kb = qk64 + (size_t)bh * NN;

  if (t < NCK) mcnt[t] = 0;
  // stage: 1024 x 16B, coalesced
  {
    const ulonglong2* __restrict__ g2 = (const ulonglong2*)kb;
    ulonglong2* s2 = (ulonglong2*)keys;
    #pragma unroll
    for (int x = 0; x < 4; x++) s2[t + 256 * x] = g2[t + 256 * x];
  }
  __syncthreads();

  const int jg = (slab << 8) | (jq << 2);                // first of 4 j's
  const unsigned long long kj0 = keys[jg];
  const unsigned long long kj1 = keys[jg + 1];
  const unsigned long long kj2 = keys[jg + 2];
  const unsigned long long kj3 = keys[jg + 3];

  const ulonglong2* __restrict__ k2 = (const ulonglong2*)(keys + kq * 512);
  int c0 = 0, c1 = 0, c2 = 0, c3 = 0;
  #pragma unroll 8
  for (int l = 0; l < 256; l++) {            // 512 keys, 2 per b128
    const ulonglong2 kk = k2[l];
    c0 += (kk.x < kj0) + (kk.y < kj0);
    c1 += (kk.x < kj1) + (kk.y < kj1);
    c2 += (kk.x < kj2) + (kk.y < kj2);
    c3 += (kk.x < kj3) + (kk.y < kj3);
  }
  cnt[kq][0 * 64 + jq] = c0;   // [u*64+jq]: lane-stride-1, conflict-free
  cnt[kq][1 * 64 + jq] = c1;
  cnt[kq][2 * 64 + jq] = c2;
  cnt[kq][3 * 64 + jq] = c3;
  __syncthreads();

  if (kq == 0) {
    #pragma unroll
    for (int u = 0; u < 4; u++) {
      const int rank = cnt[0][u * 64 + jq] + cnt[1][u * 64 + jq]
                     + cnt[2][u * 64 + jq] + cnt[3][u * 64 + jq];
      const unsigned long long kj = keys[jg + u];
      const unsigned uo = (unsigned)(kj >> 32);
      const unsigned ur = (uo & 0x80000000u) ? (uo & 0x7fffffffu) : ~uo;
      sqs [bh * NN + rank] = __uint_as_float(ur);
      idxg[bh * NN + rank] = (unsigned short)(jg + u);
      const int ck  = rank >> 7;                         // dest chunk
      const int pos = atomicAdd(&mcnt[ck], 1);
      mlist[ck][pos] = (unsigned short)((jq << 2) | u);  // local j
    }
  }
  __syncthreads();

  // chunk partial sums: wave kq serves chunks kq, kq+4, kq+8, kq+12.
  // Register accumulators; V rows coalesced (row wave-uniform, d = lane).
  const float* Vb = V + (size_t)(bh >> 3) * NN * DD;
  const int d = jq;
  #pragma unroll
  for (int cc = 0; cc < 4; cc++) {
    const int ck = kq + cc * 4;
    const int m  = mcnt[ck];
    float a1 = 0.f, a2 = 0.f, s1 = 0.f, s2 = 0.f;
    for (int e = 0; e < m; e++) {
      const int lj = mlist[ck][e];
      const unsigned long long kj = keys[(slab << 8) | lj];
      const unsigned uo = (unsigned)(kj >> 32);
      const unsigned ur = (uo & 0x80000000u) ? (uo & 0x7fffffffu) : ~uo;
      const float q  = __uint_as_float(ur);
      const float e1 = __expf(q), e2 = __expf(0.01f * q);
      const float v  = Vb[(size_t)((slab << 8) | lj) * DD + d];
      a1 += e1 * v;  a2 += e2 * v;  s1 += e1;  s2 += e2;
    }
    const size_t pb = (size_t)(bh * 8 + slab) * NCK + ck;
    PS1[pb * 64 + d] = a1;
    PS2[pb * 64 + d] = a2;
    if (d == 0) { PL1[pb] = s1;  PL2[pb] = s2; }
  }
}

// -------- Kernel 3: chunk-local prefixes in LDS + membership + out ----------
// grid BH*NCK x 256, ~80KB LDS -> 2 blocks/CU. Phase 1 rebuilds the chunk's
// exclusive prefixes in LDS; phase 2 reduces the 8 slab-partials per chunk
// (registers), range-tests membership of each i, compacts a worklist, and
// serves each i via 2 ballots + LDS row reads.
__global__ __launch_bounds__(256) void k_out2(
    const float* __restrict__ sqs, const unsigned short* __restrict__ idxg,
    const float* __restrict__ V, const float* __restrict__ ksg,
    const float* __restrict__ PS1, const float* __restrict__ PS2,
    const float* __restrict__ PL1, const float* __restrict__ PL2,
    float* __restrict__ out)
{
  __shared__ float P1l[CKS + 1][64];                 // 33 KB
  __shared__ float P2l[CKS + 1][64];                 // 33 KB
  __shared__ float sqc[CKS];                         // sorted-q chunk
  __shared__ float Ll1[CKS + 1], Ll2[CKS + 1];
  __shared__ __align__(16) unsigned char scr[12304]; // phase1 sums / worklist
  __shared__ int nwl;

  float (*ss1)[64] = (float(*)[64])scr;              // [4][64]
  float (*ss2)[64] = (float(*)[64])(scr + 1024);     // [4][64]
  float* sl1 = (float*)(scr + 2048);                 // [4]
  float* sl2 = (float*)(scr + 2064);                 // [4]
  unsigned short* wl = (unsigned short*)scr;         // [2048] (phase 2)
  float* kwl = (float*)(scr + 4096);                 // [2048] (phase 2)

  const int t  = threadIdx.x;
  const int bh = blockIdx.x >> 4;
  const int ck = blockIdx.x & 15;
  const int d  = t & 63, g = t >> 6;
  const int r0 = ck * CKS + g * 32;
  const int b  = bh >> 3, h = bh & 7;
  const float* Vb  = V + (size_t)b * NN * DD;
  const float* sqb = sqs + bh * NN;
  const unsigned short* ib = idxg + bh * NN;

  if (t < CKS) sqc[t] = sqb[ck * CKS + t];
  if (t == 0) nwl = 0;

  // pass A: wave-local sums; V stashed into P1l (same-wave readback)
  float a1 = 0.f, a2 = 0.f, s1 = 0.f, s2 = 0.f;
  #pragma unroll 8
  for (int rr = 0; rr < 32; rr++) {
    const int r = r0 + rr;
    const float qv = sqb[r];
    const float e1 = __expf(qv), e2 = __expf(0.01f * qv);
    const float v  = Vb[(size_t)ib[r] * DD + d];
    P1l[g * 32 + rr][d] = v;
    a1 += e1 * v;  a2 += e2 * v;  s1 += e1;  s2 += e2;
  }
  ss1[g][d] = a1;  ss2[g][d] = a2;
  if (d == 0) { sl1[g] = s1;  sl2[g] = s2; }
  __syncthreads();
  float o1 = 0.f, o2 = 0.f, lo1 = 0.f, lo2 = 0.f;
  for (int gg = 0; gg < g; gg++) { o1 += ss1[gg][d]; o2 += ss2[gg][d]; lo1 += sl1[gg]; lo2 += sl2[gg]; }

  // pass B: overwrite stash with chunk-local EXCLUSIVE prefixes
  a1 = o1;  a2 = o2;  s1 = lo1;  s2 = lo2;
  #pragma unroll 8
  for (int rr = 0; rr < 32; rr++) {
    const int row = g * 32 + rr;
    const float qv = sqb[r0 + rr];
    const float e1 = __expf(qv), e2 = __expf(0.01f * qv);
    const float v  = P1l[row][d];
    P1l[row][d] = a1;
    P2l[row][d] = a2;
    if (d == 0) { Ll1[row] = s1;  Ll2[row] = s2; }
    a1 += e1 * v;  a2 += e2 * v;  s1 += e1;  s2 += e2;
  }
  if (g == 3) {                       // inclusive end: loc == 128 (pos==2048)
    P1l[CKS][d] = a1;  P2l[CKS][d] = a2;
    if (d == 0) { Ll1[CKS] = s1;  Ll2[CKS] = s2; }
  }
  __syncthreads();                    // prefixes visible; scr reads done

  // ---- phase 2: cross-chunk offsets from 8 slab-partials (registers) ----
  float of1 = 0.f, of2 = 0.f, t1 = 0.f, t2 = 0.f;
  float so1 = 0.f, so2 = 0.f, lt1 = 0.f, lt2 = 0.f;
  for (int c2 = 0; c2 < NCK; c2++) {
    float v1 = 0.f, v2 = 0.f, w1 = 0.f, w2 = 0.f;
    #pragma unroll
    for (int s = 0; s < 8; s++) {
      const size_t pb = (size_t)(bh * 8 + s) * NCK + c2;
      v1 += PS1[pb * 64 + d];
      v2 += PS2[pb * 64 + d];
      w1 += PL1[pb];
      w2 += PL2[pb];
    }
    t1 += v1;  t2 += v2;  lt1 += w1;  lt2 += w2;
    if (c2 < ck) { of1 += v1; of2 += v2; so1 += w1; so2 += w2; }
  }
  // membership boundaries (count-consistent: pos>=ck*128 <=> sq[ck*128-1]<=t)
  const float qlo = ck ? sqb[ck * CKS - 1] : -__builtin_inff();
  const float qhi = (ck < NCK - 1) ? sqc[CKS - 1] : __builtin_inff();

  // membership + compaction: each thread tests 8 i's (coalesced)
  const float* kb = ksg + bh * NN;
  #pragma unroll
  for (int s = 0; s < 8; s++) {
    const int i = t + 256 * s;
    const float kv = kb[i];
    const float tt = -kv;
    if (qlo <= tt && tt < qhi) {
      const int slot = atomicAdd(&nwl, 1);
      wl[slot]  = (unsigned short)i;
      kwl[slot] = kv;
    }
  }
  __syncthreads();

  const float sq0 = sqc[d];           // loop-invariant ballot tables
  const float sq1 = sqc[64 + d];
  const int n = nwl;
  for (int e = g; e < n; e += 4) {    // wave-uniform loop; full-wave ballots
    const int i = wl[e];
    const float kv = kwl[e];
    const float tt = -kv;
    const unsigned long long b0 = __ballot(sq0 <= tt);
    const unsigned long long b1 = __ballot(sq1 <= tt);
    const int loc = __popcll(b0) + __popcll(b1);   // 0..128
    const float p1v = of1 + P1l[loc][d];
    const float p2v = of2 + P2l[loc][d];
    const float q1v = so1 + Ll1[loc];
    const float q2v = so2 + Ll2[loc];
    const float ek  = __expf(kv);
    const float ek2 = __expf(0.01f * kv);
    const float num = ek * (t1  - p1v) + ek2 * p2v;
    const float den = ek * (lt1 - q1v) + ek2 * q2v;
    out[((size_t)(b * NN + i)) * (HH * DD) + h * DD + d] = num / den;
  }
}

extern "C" void kernel_launch(void* const* d_in, const int* in_sizes, int n_in,
                              void* d_out, int out_size, void* d_ws, size_t ws_size,
                              hipStream_t stream)
{
  (void)in_sizes; (void)n_in; (void)out_size; (void)ws_size;
  const float* X  = (const float*)d_in[0];
  const float* Wv = (const float*)d_in[1];
  const float* bv = (const float*)d_in[2];
  const float* Wq = (const float*)d_in[3];
  const float* bq = (const float*)d_in[4];
  const float* Wk = (const float*)d_in[5];
  const float* bk = (const float*)d_in[6];
  float* out = (float*)d_out;

  // workspace carve-up (~6 MB)
  float* w = (float*)d_ws;
  float* V     = w;  w += (size_t)BB*NN*DD;        // 2.1 MB
  float* ksg   = w;  w += BH*NN;
  unsigned short* idxg = (unsigned short*)w;  w += BH*NN/2;
  float* PS1   = w;  w += (size_t)BH*8*NCK*DD;     // 1 MB slab-chunk partials
  float* PS2   = w;  w += (size_t)BH*8*NCK*DD;     // 1 MB
  float* PL1   = w;  w += BH*8*NCK;
  float* PL2   = w;  w += BH*8*NCK;
  float* sqs   = w;  w += BH*NN;                   // sorted q (rank-scattered)
  unsigned long long* qk64 = (unsigned long long*)w;  w += BH*NN*2;  // u64 keys

  k_vq   <<<256, 256, 0, stream>>>(X, Wv, bv, Wq, bq, Wk, bk, V, ksg, qk64);
  k_rank <<<BH*8, 256, 0, stream>>>(qk64, V, sqs, idxg, PS1, PS2, PL1, PL2);
  k_out2 <<<BH*NCK, 256, 0, stream>>>(sqs, idxg, V, ksg, PS1, PS2, PL1, PL2, out);
}

// Round 7
// 131.217 us; speedup vs baseline: 1.1076x; 1.1076x over previous
//
#include <hip/hip_runtime.h>

// Problem constants (from reference): B=4, N=2048, IN_F=512, HEADS=8, D=64
#define BB   4
#define NN   2048
#define INF  512
#define HH   8
#define DD   64
#define BH   (BB*HH)   // 32
#define NCK  16        // 128-row chunks per (b,h)
#define CKS  128       // chunk size

// ============================================================================
// A[b,h,i,j] = softmax_j( leaky_relu(q_j + k_i) ), H = A @ V.
// exp(leaky(x)) is piecewise multiplicative; sort j by q_j and the softmax
// collapses to prefix sums + position search. O(N·D).
// Harness 0xAA ws-poison (~88us, 2 fills/iter) is inside dur_us, untouchable.
// R14 FAILED: cooperative grid-sync = ~70us on 8 XCDs. Kernel boundary IS the
// cheapest grid sync. R16 FAILED: k_csum-into-k_rank fusion = serial
// mlist->key->V latency chain (+10us) to save one ~3us gap. Lesson (same as
// R11): never trade a batched sequential gather for an indirect chain.
// R17: R15 structure + in-kernel wins: k_vq 4-way k-split / 8 rows/thread
// (0.5 B/MAC LDS -> VALU-bound ~3.4us) and k_rank 8j x 256-key eighths
// (halved LDS b128 traffic -> VALU-bound ~3.5us). k_out2 keeps sqc hoist.
// ============================================================================

// ---- Kernel 1: fused V GEMM + q,k scores + sort keys -----------------------
// grid 256 x 256 thr. Block = 32 rows x 64 cols; k split 4-way (128 each).
__global__ __launch_bounds__(256) void k_vq(
    const float* __restrict__ X, const float* __restrict__ Wv,
    const float* __restrict__ bv,
    const float* __restrict__ Wq, const float* __restrict__ bq,
    const float* __restrict__ Wk, const float* __restrict__ bk,
    float* __restrict__ V, float* __restrict__ ksg,
    unsigned long long* __restrict__ qk64)
{
  __shared__ float Ws[4][64][68];   // per-quarter W chunk [k][n] — 69.6 KB
  __shared__ float red[3][32][64];  // quarters 1-3 partials — 24 KB
  __shared__ float Vs[32][65];      // reduced V rows for scores — 8.3 KB
  const int t  = threadIdx.x;
  const int kh = t >> 6;            // k quarter (one wave each)
  const int u  = t & 63;
  const int tc = u & 15;            // col quad -> cols 4tc..4tc+3
  const int rw = u >> 4;            // row group -> rows 8rw..8rw+7
  const int r0 = blockIdx.x * 32;
  float acc[8][4];
  #pragma unroll
  for (int r = 0; r < 8; r++)
    #pragma unroll
    for (int c = 0; c < 4; c++) acc[r][c] = 0.f;

  for (int kc = 0; kc < 128; kc += 64) {
    __syncthreads();
    #pragma unroll
    for (int i = 0; i < 16; i++) {   // stage this quarter's 64k x 64n W chunk
      const int e4 = u + i * 64;     // 0..1023 float4 slots
      const int k  = e4 >> 4;
      const int n4 = (e4 & 15) * 4;
      *(float4*)(&Ws[kh][k][n4]) =
          *(const float4*)(Wv + (size_t)(kh * 128 + kc + k) * DD + n4);
    }
    __syncthreads();
    const float* xp = X + (size_t)(r0 + rw * 8) * INF + kh * 128 + kc;
    #pragma unroll 2
    for (int kk = 0; kk < 64; kk += 4) {
      float4 xr[8];
      #pragma unroll
      for (int r = 0; r < 8; r++)
        xr[r] = *(const float4*)(xp + (size_t)r * INF + kk);  // 16-lane bcast
      #pragma unroll
      for (int j = 0; j < 4; j++) {
        const float4 w4 = *(const float4*)(&Ws[kh][kk + j][tc * 4]);
        #pragma unroll
        for (int r = 0; r < 8; r++) {
          const float x = (j == 0) ? xr[r].x : (j == 1) ? xr[r].y
                        : (j == 2) ? xr[r].z : xr[r].w;
          acc[r][0] += x * w4.x;  acc[r][1] += x * w4.y;
          acc[r][2] += x * w4.z;  acc[r][3] += x * w4.w;
        }
      }
    }
  }

  // ---- reduce the four k-quarters, add bias, publish V (global + LDS) ----
  // red[q][c][u]: lane-stride-1 scalar LDS ops, <=2-way conflicts (free).
  __syncthreads();
  if (kh > 0) {
    #pragma unroll
    for (int r = 0; r < 8; r++)
      #pragma unroll
      for (int c = 0; c < 4; c++)
        red[kh - 1][r * 4 + c][u] = acc[r][c];
  }
  __syncthreads();
  if (kh == 0) {
    const float4 bb = *(const float4*)(bv + tc * 4);
    #pragma unroll
    for (int r = 0; r < 8; r++) {
      float4 o;
      o.x = acc[r][0] + red[0][r*4+0][u] + red[1][r*4+0][u] + red[2][r*4+0][u] + bb.x;
      o.y = acc[r][1] + red[0][r*4+1][u] + red[1][r*4+1][u] + red[2][r*4+1][u] + bb.y;
      o.z = acc[r][2] + red[0][r*4+2][u] + red[1][r*4+2][u] + red[2][r*4+2][u] + bb.z;
      o.w = acc[r][3] + red[0][r*4+3][u] + red[1][r*4+3][u] + red[2][r*4+3][u] + bb.w;
      *(float4*)(V + (size_t)(r0 + rw * 8 + r) * DD + tc * 4) = o;
      Vs[rw * 8 + r][tc * 4]     = o.x;  Vs[rw * 8 + r][tc * 4 + 1] = o.y;
      Vs[rw * 8 + r][tc * 4 + 2] = o.z;  Vs[rw * 8 + r][tc * 4 + 3] = o.w;
    }
  }
  __syncthreads();

  // ---- scores: thread = (row, h), does both q and k dot-64 ----
  const int row = t >> 3;
  const int h   = t & 7;
  float sq = bq[h], sk = bk[h];
  #pragma unroll 8
  for (int dd = 0; dd < DD; dd++) {
    const float v = Vs[row][dd];
    sq += v * Wq[dd * HH + h];
    sk += v * Wk[dd * HH + h];
  }
  const int grow = r0 + row;
  const int b = grow >> 11, n = grow & (NN - 1);
  const int bh = b * HH + h;
  ksg[bh * NN + n] = sk;
  // tie-proof orderable key: ascending u64 order == ascending (float, idx)
  unsigned uo = __float_as_uint(sq);
  uo = (uo & 0x80000000u) ? ~uo : (uo | 0x80000000u);
  qk64[(size_t)bh * NN + n] = ((unsigned long long)uo << 32) | (unsigned)n;
}

// -------- Kernel 2: LDS-fed O(N^2) rank + scatter ---------------------------
// 256 blocks x 256 thr. Block = (bh, 256-j slab). Stage all 2048 keys (16KB);
// thread = (jq = t&31 -> 8 consecutive j's, kq = t>>5 -> 256-key eighth).
// Broadcast ds_read_b128 (2 keys) feeds 16 u64 cmp-adds -> VALU-bound; LDS
// b128 traffic halved vs the 4j/512-key split. cnt[kq][u2*32+jq]: bank = jq,
// conflict-free. Scatter spread over all 256 threads (1 j each).
__global__ __launch_bounds__(256) void k_rank(
    const unsigned long long* __restrict__ qk64,
    float* __restrict__ sqs, unsigned short* __restrict__ idxg)
{
  __shared__ __align__(16) unsigned long long keys[NN];  // 16 KB
  __shared__ int cnt[8][256];                            // 8 KB
  const int t    = threadIdx.x;
  const int bh   = blockIdx.x >> 3;
  const int slab = blockIdx.x & 7;
  const int jq   = t & 31;
  const int kq   = t >> 5;
  const unsigned long long* __restrict__ kb = qk64 + (size_t)bh * NN;

  // stage: 1024 x 16B, coalesced
  {
    const ulonglong2* __restrict__ g2 = (const ulonglong2*)kb;
    ulonglong2* s2 = (ulonglong2*)keys;
    #pragma unroll
    for (int x = 0; x < 4; x++) s2[t + 256 * x] = g2[t + 256 * x];
  }
  __syncthreads();

  const int jg = (slab << 8) | (jq << 3);                // first of 8 j's
  unsigned long long kj[8];
  #pragma unroll
  for (int u2 = 0; u2 < 8; u2++) kj[u2] = keys[jg + u2];

  int c[8] = {0, 0, 0, 0, 0, 0, 0, 0};
  const ulonglong2* __restrict__ k2 = (const ulonglong2*)(keys + kq * 256);
  #pragma unroll 8
  for (int l = 0; l < 128; l++) {            // 256 keys, 2 per b128
    const ulonglong2 kk = k2[l];
    #pragma unroll
    for (int u2 = 0; u2 < 8; u2++)
      c[u2] += (kk.x < kj[u2]) + (kk.y < kj[u2]);
  }
  #pragma unroll
  for (int u2 = 0; u2 < 8; u2++) cnt[kq][u2 * 32 + jq] = c[u2];
  __syncthreads();

  // one j per thread: rank = sum of 8 eighth-counts, then scatter
  {
    const int jl = t;                                    // local j 0..255
    const int ci = (jl & 7) * 32 + (jl >> 3);
    int rank = 0;
    #pragma unroll
    for (int q = 0; q < 8; q++) rank += cnt[q][ci];
    const unsigned long long kj2 = keys[(slab << 8) | jl];
    const unsigned uo = (unsigned)(kj2 >> 32);
    const unsigned ur = (uo & 0x80000000u) ? (uo & 0x7fffffffu) : ~uo;
    sqs [bh * NN + rank] = __uint_as_float(ur);
    idxg[bh * NN + rank] = (unsigned short)((slab << 8) | jl);
  }
}

// -------- Kernel 3a: chunk sums only (cross-block data) ---------------------
// grid BH*NCK x 256. Gather chunk's V rows, e-weighted sums -> global.
__global__ __launch_bounds__(256) void k_csum(
    const float* __restrict__ sqs, const unsigned short* __restrict__ idxg,
    const float* __restrict__ V,
    float* __restrict__ S1g, float* __restrict__ S2g,
    float* __restrict__ SL1, float* __restrict__ SL2)
{
  __shared__ float ss1[4][64], ss2[4][64];
  __shared__ float sl1[4], sl2[4];
  const int t  = threadIdx.x;
  const int bh = blockIdx.x >> 4;
  const int ck = blockIdx.x & 15;
  const int d  = t & 63, g = t >> 6;
  const int r0 = ck * CKS + g * 32;
  const float* Vb  = V + (size_t)(bh >> 3) * NN * DD;
  const float* sqb = sqs + bh * NN;
  const unsigned short* ib = idxg + bh * NN;
  float a1 = 0.f, a2 = 0.f, s1 = 0.f, s2 = 0.f;
  #pragma unroll 8
  for (int rr = 0; rr < 32; rr++) {
    const int r = r0 + rr;
    const float qv = sqb[r];
    const float e1 = __expf(qv), e2 = __expf(0.01f * qv);
    const float v  = Vb[(size_t)ib[r] * DD + d];
    a1 += e1 * v;  a2 += e2 * v;  s1 += e1;  s2 += e2;
  }
  ss1[g][d] = a1;  ss2[g][d] = a2;
  if (d == 0) { sl1[g] = s1;  sl2[g] = s2; }
  __syncthreads();
  if (g == 0) {
    S1g[(bh*NCK + ck)*64 + d] = ss1[0][d]+ss1[1][d]+ss1[2][d]+ss1[3][d];
    S2g[(bh*NCK + ck)*64 + d] = ss2[0][d]+ss2[1][d]+ss2[2][d]+ss2[3][d];
    if (d == 0) {
      SL1[bh*NCK + ck] = sl1[0]+sl1[1]+sl1[2]+sl1[3];
      SL2[bh*NCK + ck] = sl2[0]+sl2[1]+sl2[2]+sl2[3];
    }
  }
}

// -------- Kernel 3b: chunk-local prefixes in LDS + membership + out ---------
// grid BH*NCK x 256, ~80KB LDS -> 2 blocks/CU. Phase 1 rebuilds the chunk's
// exclusive prefixes in LDS (cheaper than any grid-wide fence); phase 2
// register-prefixes the 16 chunk sums, range-tests membership of each i,
// compacts a worklist, and serves each i via 2 ballots + LDS row reads.
__global__ __launch_bounds__(256) void k_out2(
    const float* __restrict__ sqs, const unsigned short* __restrict__ idxg,
    const float* __restrict__ V, const float* __restrict__ ksg,
    const float* __restrict__ S1g, const float* __restrict__ S2g,
    const float* __restrict__ SL1, const float* __restrict__ SL2,
    float* __restrict__ out)
{
  __shared__ float P1l[CKS + 1][64];                 // 33 KB
  __shared__ float P2l[CKS + 1][64];                 // 33 KB
  __shared__ float sqc[CKS];                         // sorted-q chunk
  __shared__ float Ll1[CKS + 1], Ll2[CKS + 1];
  __shared__ __align__(16) unsigned char scr[12304]; // phase1 sums / worklist
  __shared__ int nwl;

  float (*ss1)[64] = (float(*)[64])scr;              // [4][64]
  float (*ss2)[64] = (float(*)[64])(scr + 1024);     // [4][64]
  float* sl1 = (float*)(scr + 2048);                 // [4]
  float* sl2 = (float*)(scr + 2064);                 // [4]
  unsigned short* wl = (unsigned short*)scr;         // [2048] (phase 2)
  float* kwl = (float*)(scr + 4096);                 // [2048] (phase 2)

  const int t  = threadIdx.x;
  const int bh = blockIdx.x >> 4;
  const int ck = blockIdx.x & 15;
  const int d  = t & 63, g = t >> 6;
  const int r0 = ck * CKS + g * 32;
  const int b  = bh >> 3, h = bh & 7;
  const float* Vb  = V + (size_t)b * NN * DD;
  const float* sqb = sqs + bh * NN;
  const unsigned short* ib = idxg + bh * NN;

  if (t < CKS) sqc[t] = sqb[ck * CKS + t];
  if (t == 0) nwl = 0;

  // pass A: wave-local sums; V stashed into P1l (same-wave readback)
  float a1 = 0.f, a2 = 0.f, s1 = 0.f, s2 = 0.f;
  #pragma unroll 8
  for (int rr = 0; rr < 32; rr++) {
    const int r = r0 + rr;
    const float qv = sqb[r];
    const float e1 = __expf(qv), e2 = __expf(0.01f * qv);
    const float v  = Vb[(size_t)ib[r] * DD + d];
    P1l[g * 32 + rr][d] = v;
    a1 += e1 * v;  a2 += e2 * v;  s1 += e1;  s2 += e2;
  }
  ss1[g][d] = a1;  ss2[g][d] = a2;
  if (d == 0) { sl1[g] = s1;  sl2[g] = s2; }
  __syncthreads();
  float o1 = 0.f, o2 = 0.f, lo1 = 0.f, lo2 = 0.f;
  for (int gg = 0; gg < g; gg++) { o1 += ss1[gg][d]; o2 += ss2[gg][d]; lo1 += sl1[gg]; lo2 += sl2[gg]; }

  // pass B: overwrite stash with chunk-local EXCLUSIVE prefixes
  a1 = o1;  a2 = o2;  s1 = lo1;  s2 = lo2;
  #pragma unroll 8
  for (int rr = 0; rr < 32; rr++) {
    const int row = g * 32 + rr;
    const float qv = sqb[r0 + rr];
    const float e1 = __expf(qv), e2 = __expf(0.01f * qv);
    const float v  = P1l[row][d];
    P1l[row][d] = a1;
    P2l[row][d] = a2;
    if (d == 0) { Ll1[row] = s1;  Ll2[row] = s2; }
    a1 += e1 * v;  a2 += e2 * v;  s1 += e1;  s2 += e2;
  }
  if (g == 3) {                       // inclusive end: loc == 128 (pos==2048)
    P1l[CKS][d] = a1;  P2l[CKS][d] = a2;
    if (d == 0) { Ll1[CKS] = s1;  Ll2[CKS] = s2; }
  }
  __syncthreads();                    // prefixes visible; scr reads done

  // ---- phase 2: cross-chunk offsets (registers, per lane d) ----
  float of1 = 0.f, of2 = 0.f, t1 = 0.f, t2 = 0.f;
  float so1 = 0.f, so2 = 0.f, lt1 = 0.f, lt2 = 0.f;
  #pragma unroll
  for (int c2 = 0; c2 < NCK; c2++) {
    const float v1 = S1g[(bh*NCK + c2)*64 + d];
    const float v2 = S2g[(bh*NCK + c2)*64 + d];
    const float w1 = SL1[bh*NCK + c2];
    const float w2 = SL2[bh*NCK + c2];
    t1 += v1;  t2 += v2;  lt1 += w1;  lt2 += w2;
    if (c2 < ck) { of1 += v1; of2 += v2; so1 += w1; so2 += w2; }
  }
  // membership boundaries (count-consistent: pos>=ck*128 <=> sq[ck*128-1]<=t)
  const float qlo = ck ? sqb[ck * CKS - 1] : -__builtin_inff();
  const float qhi = (ck < NCK - 1) ? sqc[CKS - 1] : __builtin_inff();

  // membership + compaction: each thread tests 8 i's (coalesced)
  const float* kb = ksg + bh * NN;
  #pragma unroll
  for (int s = 0; s < 8; s++) {
    const int i = t + 256 * s;
    const float kv = kb[i];
    const float tt = -kv;
    if (qlo <= tt && tt < qhi) {
      const int slot = atomicAdd(&nwl, 1);
      wl[slot]  = (unsigned short)i;
      kwl[slot] = kv;
    }
  }
  __syncthreads();

  const float sq0 = sqc[d];           // loop-invariant ballot tables
  const float sq1 = sqc[64 + d];
  const int n = nwl;
  for (int e = g; e < n; e += 4) {    // wave-uniform loop; full-wave ballots
    const int i = wl[e];
    const float kv = kwl[e];
    const float tt = -kv;
    const unsigned long long b0 = __ballot(sq0 <= tt);
    const unsigned long long b1 = __ballot(sq1 <= tt);
    const int loc = __popcll(b0) + __popcll(b1);   // 0..128
    const float p1v = of1 + P1l[loc][d];
    const float p2v = of2 + P2l[loc][d];
    const float q1v = so1 + Ll1[loc];
    const float q2v = so2 + Ll2[loc];
    const float ek  = __expf(kv);
    const float ek2 = __expf(0.01f * kv);
    const float num = ek * (t1  - p1v) + ek2 * p2v;
    const float den = ek * (lt1 - q1v) + ek2 * q2v;
    out[((size_t)(b * NN + i)) * (HH * DD) + h * DD + d] = num / den;
  }
}

extern "C" void kernel_launch(void* const* d_in, const int* in_sizes, int n_in,
                              void* d_out, int out_size, void* d_ws, size_t ws_size,
                              hipStream_t stream)
{
  (void)in_sizes; (void)n_in; (void)out_size; (void)ws_size;
  const float* X  = (const float*)d_in[0];
  const float* Wv = (const float*)d_in[1];
  const float* bv = (const float*)d_in[2];
  const float* Wq = (const float*)d_in[3];
  const float* bq = (const float*)d_in[4];
  const float* Wk = (const float*)d_in[5];
  const float* bk = (const float*)d_in[6];
  float* out = (float*)d_out;

  // workspace carve-up (~3.5 MB)
  float* w = (float*)d_ws;
  float* V     = w;  w += (size_t)BB*NN*DD;        // 2.1 MB
  float* ksg   = w;  w += BH*NN;
  unsigned short* idxg = (unsigned short*)w;  w += BH*NN/2;
  float* S1g   = w;  w += (size_t)BH*NCK*DD;
  float* S2g   = w;  w += (size_t)BH*NCK*DD;
  float* SL1   = w;  w += BH*NCK;
  float* SL2   = w;  w += BH*NCK;
  float* sqs   = w;  w += BH*NN;                   // sorted q (rank-scattered)
  unsigned long long* qk64 = (unsigned long long*)w;  w += BH*NN*2;  // u64 keys

  k_vq   <<<256, 256, 0, stream>>>(X, Wv, bv, Wq, bq, Wk, bk, V, ksg, qk64);
  k_rank <<<BH*8, 256, 0, stream>>>(qk64, sqs, idxg);
  k_csum <<<BH*NCK, 256, 0, stream>>>(sqs, idxg, V, S1g, S2g, SL1, SL2);
  k_out2 <<<BH*NCK, 256, 0, stream>>>(sqs, idxg, V, ksg, S1g, S2g, SL1, SL2, out);
}